// Round 1
// baseline (79.843 us; speedup 1.0000x reference)
//
#include <hip/hip_runtime.h>
#include <hip/hip_bf16.h>

#define B_   16
#define T_   8192
#define DIN  4
#define H_   256
#define C_   11
#define KCH  256            // chunks per batch
#define LCH  32             // steps per chunk (T_/KCH)
#define NC   (B_*KCH)       // total chunks

// ---------------------------------------------------------------------------
// K1: encoder — em[b,t,c] = (relu(seq@Wenc+benc)@Wemit+bemit)[c]; store exp(em)
// padded to 12 floats per row. 2 rows per thread, weights staged in LDS.
// ---------------------------------------------------------------------------
__global__ __launch_bounds__(256) void k_em(
    const float* __restrict__ seq, const float* __restrict__ Wenc,
    const float* __restrict__ benc, const float* __restrict__ Wemit,
    const float* __restrict__ bemit, float* __restrict__ expem)
{
    __shared__ float ldsEnc[H_ * 4];    // [h][d]
    __shared__ float ldsBenc[H_];
    __shared__ float ldsEmit[H_ * 12];  // [h][c] padded to 12
    int tid = threadIdx.x;
    for (int i = tid; i < H_ * 4; i += 256)
        ldsEnc[i] = Wenc[(i & 3) * H_ + (i >> 2)];
    for (int i = tid; i < H_; i += 256)
        ldsBenc[i] = benc[i];
    for (int i = tid; i < H_ * 12; i += 256) {
        int h = i / 12, c = i - h * 12;
        ldsEmit[i] = (c < C_) ? Wemit[h * C_ + c] : 0.f;
    }
    __syncthreads();

    int r0 = blockIdx.x * 512 + tid;          // rows r0 and r0+256
    float4 x0 = *(const float4*)(seq + (size_t)r0 * 4);
    float4 x1 = *(const float4*)(seq + (size_t)(r0 + 256) * 4);
    float acc0[C_], acc1[C_];
#pragma unroll
    for (int c = 0; c < C_; c++) { float bv = bemit[c]; acc0[c] = bv; acc1[c] = bv; }

    const float4* enc4 = (const float4*)ldsEnc;
#pragma unroll 4
    for (int h = 0; h < H_; h++) {
        float4 w = enc4[h];
        float hb = ldsBenc[h];
        float h0 = fmaf(x0.x, w.x, fmaf(x0.y, w.y, fmaf(x0.z, w.z, fmaf(x0.w, w.w, hb))));
        float h1 = fmaf(x1.x, w.x, fmaf(x1.y, w.y, fmaf(x1.z, w.z, fmaf(x1.w, w.w, hb))));
        h0 = fmaxf(h0, 0.f);
        h1 = fmaxf(h1, 0.f);
#pragma unroll
        for (int c = 0; c < C_; c++) {
            float wv = ldsEmit[h * 12 + c];
            acc0[c] = fmaf(h0, wv, acc0[c]);
            acc1[c] = fmaf(h1, wv, acc1[c]);
        }
    }

    float e0[12], e1[12];
#pragma unroll
    for (int c = 0; c < C_; c++) { e0[c] = __expf(acc0[c]); e1[c] = __expf(acc1[c]); }
    e0[11] = 0.f; e1[11] = 0.f;
    float4* o0 = (float4*)(expem + (size_t)r0 * 12);
    float4* o1 = (float4*)(expem + (size_t)(r0 + 256) * 12);
    o0[0] = make_float4(e0[0], e0[1], e0[2], e0[3]);
    o0[1] = make_float4(e0[4], e0[5], e0[6], e0[7]);
    o0[2] = make_float4(e0[8], e0[9], e0[10], e0[11]);
    o1[0] = make_float4(e1[0], e1[1], e1[2], e1[3]);
    o1[1] = make_float4(e1[4], e1[5], e1[6], e1[7]);
    o1[2] = make_float4(e1[8], e1[9], e1[10], e1[11]);
}

// ---------------------------------------------------------------------------
// K2: per-chunk transfer matrices in probability domain with per-row rescale.
// Lane = (chunk, row): row of G kept in registers; expT (121) in registers.
// g_new[j] = (sum_k g[k]*expT[k][j]) * expem[t][j], masked by t<len.
// Output: normalized row + log-scale, layout [chunk][row][12].
// ---------------------------------------------------------------------------
__global__ __launch_bounds__(256) void k_chunks(
    const float* __restrict__ trans, const int* __restrict__ lengths,
    const float* __restrict__ expem, float* __restrict__ G)
{
    int tid = threadIdx.x;
    int lane = tid & 63, w = tid >> 6;
    int ciw = lane / C_;            // chunk-in-wave 0..4 (5*11=55 active lanes)
    int i = lane - ciw * C_;        // row index
    int cid = blockIdx.x * 20 + w * 5 + ciw;
    if (ciw >= 5 || cid >= NC) return;

    int b = cid >> 8;               // KCH = 256
    int k = cid & (KCH - 1);
    int t0 = 1 + k * LCH;
    int len = lengths[b];

    float eT[121];
#pragma unroll
    for (int z = 0; z < 121; z++) eT[z] = __expf(trans[z]);

    float g[C_];
#pragma unroll
    for (int j = 0; j < C_; j++) g[j] = (j == i) ? 1.f : 0.f;
    float ls = 0.f;

    const float* emb = expem + (size_t)b * T_ * 12;
    int t = t0;
#pragma unroll 1
    for (int su = 0; su < LCH / 4; su++) {
#pragma unroll
        for (int ss = 0; ss < 4; ss++) {
            int tc = (t < T_) ? t : (T_ - 1);
            const float4* er = (const float4*)(emb + tc * 12);
            float4 eA = er[0], eB = er[1], eC = er[2];
            float nxt[C_];
#pragma unroll
            for (int j = 0; j < C_; j++) nxt[j] = g[0] * eT[j];
#pragma unroll
            for (int kk = 1; kk < C_; kk++)
#pragma unroll
                for (int j = 0; j < C_; j++)
                    nxt[j] = fmaf(g[kk], eT[kk * C_ + j], nxt[j]);
            float emv[12] = {eA.x, eA.y, eA.z, eA.w, eB.x, eB.y, eB.z, eB.w,
                             eC.x, eC.y, eC.z, eC.w};
            bool act = (t < len);
#pragma unroll
            for (int j = 0; j < C_; j++) g[j] = act ? nxt[j] * emv[j] : g[j];
            t++;
        }
        float s = 0.f;
#pragma unroll
        for (int j = 0; j < C_; j++) s += g[j];
        float r = 1.f / s;
#pragma unroll
        for (int j = 0; j < C_; j++) g[j] *= r;
        ls += __logf(s);
    }

    float* o = G + (size_t)cid * 132 + i * 12;
#pragma unroll
    for (int j = 0; j < C_; j++) o[j] = g[j];
    o[11] = ls;
}

// ---------------------------------------------------------------------------
// K3: per-batch binary-tree combine of chunk matrices (prob domain, scale
// folding), then den[b] = lse(alpha0 . G_total + end_trans).
// ---------------------------------------------------------------------------
__global__ __launch_bounds__(256) void k_combine(
    const float* __restrict__ start_trans, const float* __restrict__ end_trans,
    const float* __restrict__ expem, float* __restrict__ G0,
    float* __restrict__ G1, float* __restrict__ dens)
{
    int b = blockIdx.x, tid = threadIdx.x;
    float* pin  = G0 + (size_t)b * KCH * 132;
    float* pout = G1 + (size_t)b * KCH * 132;
    int n = KCH;
    while (n > 1) {
        int np = n >> 1;
        for (int task = tid; task < np * C_; task += 256) {
            int p = task / C_, i = task - p * C_;
            const float* A  = pin + (size_t)(2 * p) * 132 + i * 12;
            const float* Bm = pin + (size_t)(2 * p + 1) * 132;
            float als = A[11];
            float m = Bm[11];
#pragma unroll
            for (int kk = 1; kk < C_; kk++) m = fmaxf(m, Bm[kk * 12 + 11]);
            float wv[C_];
#pragma unroll
            for (int kk = 0; kk < C_; kk++)
                wv[kk] = A[kk] * __expf(Bm[kk * 12 + 11] - m);
            float out[C_];
#pragma unroll
            for (int j = 0; j < C_; j++) out[j] = wv[0] * Bm[j];
#pragma unroll
            for (int kk = 1; kk < C_; kk++)
#pragma unroll
                for (int j = 0; j < C_; j++)
                    out[j] = fmaf(wv[kk], Bm[kk * 12 + j], out[j]);
            float s = 0.f;
#pragma unroll
            for (int j = 0; j < C_; j++) s += out[j];
            float r = 1.f / s;
            float* O = pout + (size_t)p * 132 + i * 12;
#pragma unroll
            for (int j = 0; j < C_; j++) O[j] = out[j] * r;
            O[11] = als + m + __logf(s);
        }
        __syncthreads();
        n = np;
        float* tmp = pin; pin = pout; pout = tmp;
    }
    if (tid == 0) {
        const float* Cm = pin;                    // final matrix
        const float* em0 = expem + (size_t)b * T_ * 12;
        float av[C_];
        float mm = -1e30f;
#pragma unroll
        for (int i2 = 0; i2 < C_; i2++) {
            av[i2] = start_trans[i2] + __logf(em0[i2]) + Cm[i2 * 12 + 11];
            mm = fmaxf(mm, av[i2]);
        }
        float S[C_];
#pragma unroll
        for (int j = 0; j < C_; j++) S[j] = 0.f;
#pragma unroll
        for (int i2 = 0; i2 < C_; i2++) {
            float e = __expf(av[i2] - mm);
#pragma unroll
            for (int j = 0; j < C_; j++) S[j] = fmaf(e, Cm[i2 * 12 + j], S[j]);
        }
        float tot = 0.f;
#pragma unroll
        for (int j = 0; j < C_; j++) tot += S[j] * __expf(end_trans[j]);
        dens[b] = __logf(tot) + mm;
    }
}

// ---------------------------------------------------------------------------
// K_num: numerator path reduction (masked gather-sum over t).
// ---------------------------------------------------------------------------
__global__ __launch_bounds__(256) void k_num(
    const float* __restrict__ trans, const float* __restrict__ start_trans,
    const float* __restrict__ end_trans, const int* __restrict__ lengths,
    const int* __restrict__ labels, const float* __restrict__ expem,
    float* __restrict__ nums)
{
    int b = blockIdx.x >> 3, slice = blockIdx.x & 7;
    int tid = threadIdx.x;
    int len = lengths[b];
    const int* lab = labels + (size_t)b * T_;
    const float* emb = expem + (size_t)b * T_ * 12;
    float acc = 0.f;
    for (int tt = tid; tt < T_ / 8; tt += 256) {
        int t = slice * (T_ / 8) + tt + 1;
        if (t < T_ && t < len) {
            int tp = lab[t - 1]; tp = (tp == -100) ? 0 : tp;
            int tg = lab[t];     tg = (tg == -100) ? 0 : tg;
            acc += trans[tp * C_ + tg] + __logf(emb[t * 12 + tg]);
        }
    }
    for (int off = 32; off > 0; off >>= 1) acc += __shfl_down(acc, off);
    __shared__ float wsum[4];
    if ((tid & 63) == 0) wsum[tid >> 6] = acc;
    __syncthreads();
    if (tid == 0) {
        float tot = wsum[0] + wsum[1] + wsum[2] + wsum[3];
        if (slice == 0) {
            int t0g = lab[0];      t0g = (t0g == -100) ? 0 : t0g;
            int tl = lab[len - 1]; tl = (tl == -100) ? 0 : tl;
            tot += start_trans[t0g] + __logf(emb[t0g]) + end_trans[tl];
        }
        atomicAdd(&nums[b], tot);
    }
}

// ---------------------------------------------------------------------------
// K4: final scalar: -mean(num - den)
// ---------------------------------------------------------------------------
__global__ void k_final(const float* __restrict__ nums,
                        const float* __restrict__ dens,
                        float* __restrict__ out)
{
    int tid = threadIdx.x;
    float v = (tid < B_) ? (nums[tid] - dens[tid]) : 0.f;
    for (int off = 32; off > 0; off >>= 1) v += __shfl_down(v, off);
    if (tid == 0) out[0] = -v / (float)B_;
}

extern "C" void kernel_launch(void* const* d_in, const int* in_sizes, int n_in,
                              void* d_out, int out_size, void* d_ws, size_t ws_size,
                              hipStream_t stream) {
    const float* seq    = (const float*)d_in[0];
    const float* Wenc   = (const float*)d_in[1];
    const float* benc   = (const float*)d_in[2];
    const float* Wemit  = (const float*)d_in[3];
    const float* bemit  = (const float*)d_in[4];
    const float* startt = (const float*)d_in[5];
    const float* trans  = (const float*)d_in[6];
    const float* endt   = (const float*)d_in[7];
    const int*   lengths= (const int*)d_in[8];
    const int*   labels = (const int*)d_in[9];

    float* ws    = (float*)d_ws;
    float* expem = ws;                                  // B*T*12
    float* G0    = expem + (size_t)B_ * T_ * 12;        // NC*132
    float* G1    = G0 + (size_t)NC * 132;               // NC*132
    float* nums  = G1 + (size_t)NC * 132;               // B
    float* dens  = nums + B_;                           // B
    float* out   = (float*)d_out;

    hipMemsetAsync(nums, 0, B_ * sizeof(float), stream);
    k_em<<<256, 256, 0, stream>>>(seq, Wenc, benc, Wemit, bemit, expem);
    k_chunks<<<(NC + 19) / 20, 256, 0, stream>>>(trans, lengths, expem, G0);
    k_num<<<B_ * 8, 256, 0, stream>>>(trans, startt, endt, lengths, labels, expem, nums);
    k_combine<<<B_, 256, 0, stream>>>(startt, endt, expem, G0, G1, dens);
    k_final<<<1, 64, 0, stream>>>(nums, dens, out);
}

// Round 2
// 66.519 us; speedup vs baseline: 1.2003x; 1.2003x over previous
//
#include <hip/hip_runtime.h>
#include <hip/hip_bf16.h>

#define B_   16
#define T_   8192
#define H_   256
#define C_   11
#define KCH  256            // chunks per batch
#define LCH  32             // steps per chunk (T_/KCH)
#define NC   (B_*KCH)       // total chunks

// ---------------------------------------------------------------------------
// numerator contribution of one (b,t) position, using em row in registers
// ---------------------------------------------------------------------------
__device__ __forceinline__ float numContrib(const float* acc, int t, int len,
    const int* __restrict__ lab, const float* __restrict__ trans,
    const float* __restrict__ startt, const float* __restrict__ endt)
{
    int tg = lab[t]; if (tg < 0) tg = 0;
    float emt = acc[0];
#pragma unroll
    for (int c = 1; c < C_; c++) emt = (tg == c) ? acc[c] : emt;
    float r = 0.f;
    if (t == 0) {
        r += startt[tg] + emt;
    } else if (t < len) {
        int tp = lab[t - 1]; if (tp < 0) tp = 0;
        r += trans[tp * C_ + tg] + emt;
    }
    if (t == len - 1) r += endt[tg];
    return r;
}

// ---------------------------------------------------------------------------
// K1: encoder + emissions + FUSED numerator.
// em[b,t,c] = (relu(seq@Wenc+benc)@Wemit+bemit)[c]; stores exp(em) padded to
// 12 floats/row. Each block = 512 rows of ONE batch; block writes its own
// numpart slot (no atomics, no memset).
// ---------------------------------------------------------------------------
__global__ __launch_bounds__(256) void k_em(
    const float* __restrict__ seq, const float* __restrict__ Wenc,
    const float* __restrict__ benc, const float* __restrict__ Wemit,
    const float* __restrict__ bemit, const float* __restrict__ trans,
    const float* __restrict__ startt, const float* __restrict__ endt,
    const int* __restrict__ lengths, const int* __restrict__ labels,
    float* __restrict__ expem, float* __restrict__ numpart)
{
    __shared__ float ldsEnc[H_ * 4];    // [h][d]
    __shared__ float ldsBenc[H_];
    __shared__ float ldsEmit[H_ * 12];  // [h][c] padded to 12 (float4-able)
    __shared__ float red[4];
    int tid = threadIdx.x;
    for (int i = tid; i < H_ * 4; i += 256)
        ldsEnc[i] = Wenc[(i & 3) * H_ + (i >> 2)];
    for (int i = tid; i < H_; i += 256)
        ldsBenc[i] = benc[i];
    for (int i = tid; i < H_ * 12; i += 256) {
        int h = i / 12, c = i - h * 12;
        ldsEmit[i] = (c < C_) ? Wemit[h * C_ + c] : 0.f;
    }
    __syncthreads();

    int r0 = blockIdx.x * 512 + tid;          // rows r0 and r0+256
    float4 x0 = *(const float4*)(seq + (size_t)r0 * 4);
    float4 x1 = *(const float4*)(seq + (size_t)(r0 + 256) * 4);
    float acc0[C_], acc1[C_];
#pragma unroll
    for (int c = 0; c < C_; c++) { float bv = bemit[c]; acc0[c] = bv; acc1[c] = bv; }

    const float4* enc4 = (const float4*)ldsEnc;
#pragma unroll 2
    for (int h = 0; h < H_; h++) {
        float4 w = enc4[h];
        float hb = ldsBenc[h];
        float h0 = fmaf(x0.x, w.x, fmaf(x0.y, w.y, fmaf(x0.z, w.z, fmaf(x0.w, w.w, hb))));
        float h1 = fmaf(x1.x, w.x, fmaf(x1.y, w.y, fmaf(x1.z, w.z, fmaf(x1.w, w.w, hb))));
        h0 = fmaxf(h0, 0.f);
        h1 = fmaxf(h1, 0.f);
        const float4* e4 = (const float4*)(ldsEmit + h * 12);
        float4 ea = e4[0], eb = e4[1], ec = e4[2];
        acc0[0] = fmaf(h0, ea.x, acc0[0]);  acc1[0] = fmaf(h1, ea.x, acc1[0]);
        acc0[1] = fmaf(h0, ea.y, acc0[1]);  acc1[1] = fmaf(h1, ea.y, acc1[1]);
        acc0[2] = fmaf(h0, ea.z, acc0[2]);  acc1[2] = fmaf(h1, ea.z, acc1[2]);
        acc0[3] = fmaf(h0, ea.w, acc0[3]);  acc1[3] = fmaf(h1, ea.w, acc1[3]);
        acc0[4] = fmaf(h0, eb.x, acc0[4]);  acc1[4] = fmaf(h1, eb.x, acc1[4]);
        acc0[5] = fmaf(h0, eb.y, acc0[5]);  acc1[5] = fmaf(h1, eb.y, acc1[5]);
        acc0[6] = fmaf(h0, eb.z, acc0[6]);  acc1[6] = fmaf(h1, eb.z, acc1[6]);
        acc0[7] = fmaf(h0, eb.w, acc0[7]);  acc1[7] = fmaf(h1, eb.w, acc1[7]);
        acc0[8] = fmaf(h0, ec.x, acc0[8]);  acc1[8] = fmaf(h1, ec.x, acc1[8]);
        acc0[9] = fmaf(h0, ec.y, acc0[9]);  acc1[9] = fmaf(h1, ec.y, acc1[9]);
        acc0[10]= fmaf(h0, ec.z, acc0[10]); acc1[10]= fmaf(h1, ec.z, acc1[10]);
    }

    // ---- fused numerator (uses em BEFORE exp: exact log-space values) ----
    int b = blockIdx.x >> 4;
    int len = lengths[b];
    const int* lab = labels + (size_t)b * T_;
    int tl0 = ((blockIdx.x & 15) << 9) + tid;
    float nacc = numContrib(acc0, tl0, len, lab, trans, startt, endt)
               + numContrib(acc1, tl0 + 256, len, lab, trans, startt, endt);

    // ---- exp + store ----
    float e0[12], e1[12];
#pragma unroll
    for (int c = 0; c < C_; c++) { e0[c] = __expf(acc0[c]); e1[c] = __expf(acc1[c]); }
    e0[11] = 0.f; e1[11] = 0.f;
    float4* o0 = (float4*)(expem + (size_t)r0 * 12);
    float4* o1 = (float4*)(expem + (size_t)(r0 + 256) * 12);
    o0[0] = make_float4(e0[0], e0[1], e0[2], e0[3]);
    o0[1] = make_float4(e0[4], e0[5], e0[6], e0[7]);
    o0[2] = make_float4(e0[8], e0[9], e0[10], e0[11]);
    o1[0] = make_float4(e1[0], e1[1], e1[2], e1[3]);
    o1[1] = make_float4(e1[4], e1[5], e1[6], e1[7]);
    o1[2] = make_float4(e1[8], e1[9], e1[10], e1[11]);

    // ---- block reduce numerator ----
#pragma unroll
    for (int off = 32; off > 0; off >>= 1) nacc += __shfl_down(nacc, off);
    if ((tid & 63) == 0) red[tid >> 6] = nacc;
    __syncthreads();
    if (tid == 0) numpart[blockIdx.x] = red[0] + red[1] + red[2] + red[3];
}

// ---------------------------------------------------------------------------
// K2: per-chunk transfer matrices in probability domain with per-row rescale.
// Lane = (chunk, row). Software-pipelined: next step's em row loads while the
// current matvec computes (only ~0.8 waves/SIMD, so latency must hide in ILP).
// ---------------------------------------------------------------------------
__global__ __launch_bounds__(256) void k_chunks(
    const float* __restrict__ trans, const int* __restrict__ lengths,
    const float* __restrict__ expem, float* __restrict__ G)
{
    int tid = threadIdx.x;
    int lane = tid & 63, w = tid >> 6;
    int ciw = lane / C_;            // chunk-in-wave 0..4 (55/64 lanes active)
    int i = lane - ciw * C_;        // row index
    int cid = blockIdx.x * 20 + w * 5 + ciw;
    if (ciw >= 5 || cid >= NC) return;

    int b = cid >> 8;
    int k = cid & (KCH - 1);
    int t0 = 1 + k * LCH;
    int len = lengths[b];

    float eT[121];
#pragma unroll
    for (int z = 0; z < 121; z++) eT[z] = __expf(trans[z]);

    float g[C_];
#pragma unroll
    for (int j = 0; j < C_; j++) g[j] = (j == i) ? 1.f : 0.f;
    float ls = 0.f;

    const float* emb = expem + (size_t)b * T_ * 12;
    int tc0 = (t0 < T_) ? t0 : (T_ - 1);
    const float4* er0 = (const float4*)(emb + tc0 * 12);
    float4 cA = er0[0], cB = er0[1], cC = er0[2];

#pragma unroll 1
    for (int su = 0; su < LCH / 4; su++) {
#pragma unroll
        for (int ss = 0; ss < 4; ss++) {
            int t = t0 + su * 4 + ss;
            int tn = t + 1; tn = (tn < T_) ? tn : (T_ - 1);
            const float4* ern = (const float4*)(emb + tn * 12);
            float4 nA = ern[0], nB = ern[1], nC = ern[2];   // prefetch next step
            float nxt[C_];
#pragma unroll
            for (int j = 0; j < C_; j++) nxt[j] = g[0] * eT[j];
#pragma unroll
            for (int kk = 1; kk < C_; kk++)
#pragma unroll
                for (int j = 0; j < C_; j++)
                    nxt[j] = fmaf(g[kk], eT[kk * C_ + j], nxt[j]);
            float emv[C_] = {cA.x, cA.y, cA.z, cA.w, cB.x, cB.y, cB.z, cB.w,
                             cC.x, cC.y, cC.z};
            bool act = (t < len);
#pragma unroll
            for (int j = 0; j < C_; j++) g[j] = act ? nxt[j] * emv[j] : g[j];
            cA = nA; cB = nB; cC = nC;
        }
        float s = 0.f;
#pragma unroll
        for (int j = 0; j < C_; j++) s += g[j];
        float r = 1.f / s;
#pragma unroll
        for (int j = 0; j < C_; j++) g[j] *= r;
        ls += __logf(s);
    }

    float* o = G + (size_t)cid * 132 + i * 12;
#pragma unroll
    for (int j = 0; j < C_; j++) o[j] = g[j];
    o[11] = ls;
}

// ---------------------------------------------------------------------------
// K3: per-batch tree combine ENTIRELY IN LDS (135 KiB of gfx950's 160 KiB),
// then den[b]. In-place pair combine (write slot is even multiple of 2*stride,
// B-read slots are odd multiples of stride -> disjoint within a level).
// ---------------------------------------------------------------------------
__global__ __launch_bounds__(256, 1) void k_comb(
    const float* __restrict__ startt, const float* __restrict__ endt,
    const float* __restrict__ expem, const float* __restrict__ G0,
    float* __restrict__ dens)
{
    __shared__ float M[KCH * 132];     // 135168 bytes
    int b = blockIdx.x, tid = threadIdx.x;
    const float4* src = (const float4*)(G0 + (size_t)b * KCH * 132);
    float4* dst = (float4*)M;
#pragma unroll 4
    for (int idx = tid; idx < KCH * 132 / 4; idx += 256) dst[idx] = src[idx];
    __syncthreads();

    for (int stride = 1; stride < KCH; stride <<= 1) {
        int npair = KCH / (2 * stride);
        for (int task = tid; task < npair * C_; task += 256) {
            int p = task / C_, i = task - p * C_;
            float* A  = M + (size_t)(2 * stride * p) * 132;
            float* Bm = M + (size_t)(2 * stride * p + stride) * 132;
            float a[C_];
#pragma unroll
            for (int kk = 0; kk < C_; kk++) a[kk] = A[i * 12 + kk];
            float als = A[i * 12 + 11];
            float m = Bm[11];
#pragma unroll
            for (int kk = 1; kk < C_; kk++) m = fmaxf(m, Bm[kk * 12 + 11]);
            float wv[C_];
#pragma unroll
            for (int kk = 0; kk < C_; kk++)
                wv[kk] = a[kk] * __expf(Bm[kk * 12 + 11] - m);
            float out[C_];
#pragma unroll
            for (int j = 0; j < C_; j++) out[j] = wv[0] * Bm[j];
#pragma unroll
            for (int kk = 1; kk < C_; kk++)
#pragma unroll
                for (int j = 0; j < C_; j++)
                    out[j] = fmaf(wv[kk], Bm[kk * 12 + j], out[j]);
            float s = 0.f;
#pragma unroll
            for (int j = 0; j < C_; j++) s += out[j];
            float rr = 1.f / s;
#pragma unroll
            for (int j = 0; j < C_; j++) A[i * 12 + j] = out[j] * rr;
            A[i * 12 + 11] = als + m + __logf(s);
        }
        __syncthreads();
    }

    if (tid == 0) {
        const float* Cm = M;                      // total matrix in slot 0
        const float* em0 = expem + (size_t)b * T_ * 12;
        float av[C_];
        float mm = -1e30f;
#pragma unroll
        for (int i2 = 0; i2 < C_; i2++) {
            av[i2] = startt[i2] + __logf(em0[i2]) + Cm[i2 * 12 + 11];
            mm = fmaxf(mm, av[i2]);
        }
        float S[C_];
#pragma unroll
        for (int j = 0; j < C_; j++) S[j] = 0.f;
#pragma unroll
        for (int i2 = 0; i2 < C_; i2++) {
            float e = __expf(av[i2] - mm);
#pragma unroll
            for (int j = 0; j < C_; j++) S[j] = fmaf(e, Cm[i2 * 12 + j], S[j]);
        }
        float tot = 0.f;
#pragma unroll
        for (int j = 0; j < C_; j++) tot += S[j] * __expf(endt[j]);
        dens[b] = __logf(tot) + mm;
    }
}

// ---------------------------------------------------------------------------
// K4: final scalar: -(sum(numpart) - sum(dens)) / B
// ---------------------------------------------------------------------------
__global__ __launch_bounds__(256) void k_final(
    const float* __restrict__ numpart, const float* __restrict__ dens,
    float* __restrict__ out)
{
    __shared__ float red[4];
    int tid = threadIdx.x;
    float v = numpart[tid];
    if (tid < B_) v -= dens[tid];
#pragma unroll
    for (int off = 32; off > 0; off >>= 1) v += __shfl_down(v, off);
    if ((tid & 63) == 0) red[tid >> 6] = v;
    __syncthreads();
    if (tid == 0) out[0] = -(red[0] + red[1] + red[2] + red[3]) / (float)B_;
}

extern "C" void kernel_launch(void* const* d_in, const int* in_sizes, int n_in,
                              void* d_out, int out_size, void* d_ws, size_t ws_size,
                              hipStream_t stream) {
    const float* seq    = (const float*)d_in[0];
    const float* Wenc   = (const float*)d_in[1];
    const float* benc   = (const float*)d_in[2];
    const float* Wemit  = (const float*)d_in[3];
    const float* bemit  = (const float*)d_in[4];
    const float* startt = (const float*)d_in[5];
    const float* trans  = (const float*)d_in[6];
    const float* endt   = (const float*)d_in[7];
    const int*   lengths= (const int*)d_in[8];
    const int*   labels = (const int*)d_in[9];

    float* ws      = (float*)d_ws;
    float* expem   = ws;                                  // B*T*12
    float* G0      = expem + (size_t)B_ * T_ * 12;        // NC*132
    float* numpart = G0 + (size_t)NC * 132;               // 256
    float* dens    = numpart + 256;                       // B
    float* out     = (float*)d_out;

    k_em<<<256, 256, 0, stream>>>(seq, Wenc, benc, Wemit, bemit, trans,
                                  startt, endt, lengths, labels, expem, numpart);
    k_chunks<<<(NC + 19) / 20, 256, 0, stream>>>(trans, lengths, expem, G0);
    k_comb<<<B_, 256, 0, stream>>>(startt, endt, expem, G0, dens);
    k_final<<<1, 256, 0, stream>>>(numpart, dens, out);
}